// Round 6
// baseline (129588.379 us; speedup 1.0000x reference)
//
#include <hip/hip_runtime.h>
#include <hip/hip_bf16.h>
#include <cstdint>

// Problem dims
#define TE    512
#define SD    128
#define NB    512   // persistent grid

typedef unsigned short u16;
typedef u16 u16x4 __attribute__((ext_vector_type(4)));
typedef u16 u16x8 __attribute__((ext_vector_type(8)));

// State region offsets (floats), relative to st pointer
#define QO    0          // [32][1024]
#define SCO   32768      // [32][512]
#define EBO   49152      // tier2: eb buffer; tier1: grid-barrier region (ints)
#define CTXO  81920      // [32][1024]
#define YO    114688     // [32][128]
#define H0O   118784     // [2][32][512]
#define C0O   151552
#define H1O   184320
#define C1O   217088
#define ST_N  249856

__device__ __forceinline__ float b2f(u16 v) { return __uint_as_float(((unsigned)v) << 16); }
__device__ __forceinline__ u16 f2b(float f) {
  unsigned u = __float_as_uint(f);
  return (u16)((u + 0x7FFFu + ((u >> 16) & 1u)) >> 16);
}
__device__ __forceinline__ float tanh_f(float x) {
  float xc = fminf(12.f, fmaxf(-12.f, x));
  float e  = __expf(2.f * xc);
  return __fdividef(e - 1.f, e + 1.f);
}
__device__ __forceinline__ float sigm(float x) {
  float xc = fminf(30.f, fmaxf(-30.f, x));
  return __fdividef(1.f, 1.f + __expf(-xc));
}

// ---------------- NT GEMM: out = A @ B^T (fp32 in, bf16 out), 16384x1024x1024 ----------------
__global__ __launch_bounds__(256)
void gemm_nt(const float* __restrict__ A, const float* __restrict__ B, u16* __restrict__ outp) {
  __shared__ float Asm[16][68], Bsm[16][68];
  const int tid = threadIdx.x;
  const int tm = blockIdx.x * 64, tn = blockIdx.y * 64;
  const int lr = tid >> 2, lc = (tid & 3) * 4;
  const int tx = tid & 15, ty = tid >> 4;
  float acc[4][4] = {};
  for (int k0 = 0; k0 < 1024; k0 += 16) {
    float4 av = *(const float4*)(&A[(long)(tm + lr) * 1024 + k0 + lc]);
    float4 bv = *(const float4*)(&B[(long)(tn + lr) * 1024 + k0 + lc]);
    Asm[lc][lr] = av.x; Asm[lc + 1][lr] = av.y; Asm[lc + 2][lr] = av.z; Asm[lc + 3][lr] = av.w;
    Bsm[lc][lr] = bv.x; Bsm[lc + 1][lr] = bv.y; Bsm[lc + 2][lr] = bv.z; Bsm[lc + 3][lr] = bv.w;
    __syncthreads();
#pragma unroll
    for (int kk = 0; kk < 16; ++kk) {
      float4 a4 = *(const float4*)(&Asm[kk][ty * 4]);
      float4 b4 = *(const float4*)(&Bsm[kk][tx * 4]);
      acc[0][0] += a4.x * b4.x; acc[0][1] += a4.x * b4.y; acc[0][2] += a4.x * b4.z; acc[0][3] += a4.x * b4.w;
      acc[1][0] += a4.y * b4.x; acc[1][1] += a4.y * b4.y; acc[1][2] += a4.y * b4.z; acc[1][3] += a4.y * b4.w;
      acc[2][0] += a4.z * b4.x; acc[2][1] += a4.z * b4.y; acc[2][2] += a4.z * b4.z; acc[2][3] += a4.z * b4.w;
      acc[3][0] += a4.w * b4.x; acc[3][1] += a4.w * b4.y; acc[3][2] += a4.w * b4.z; acc[3][3] += a4.w * b4.w;
    }
    __syncthreads();
  }
#pragma unroll
  for (int i = 0; i < 4; ++i)
#pragma unroll
    for (int j = 0; j < 4; ++j)
      outp[(long)(tm + ty * 4 + i) * 1024 + tn + tx * 4 + j] = f2b(acc[i][j]);
}

// ---------------- init: h/c -> parity-0 state, zero y, zero barrier region ----------------
__global__ __launch_bounds__(256)
void init_state(const float* __restrict__ h0, const float* __restrict__ c0, float* __restrict__ st) {
  int i = blockIdx.x * 256 + threadIdx.x;   // 16384 threads
  st[H0O + i] = h0[i];
  st[H1O + i] = h0[16384 + i];
  st[C0O + i] = c0[i];
  st[C1O + i] = c0[16384 + i];
  if (i < 4096) st[YO + i] = 0.f;
  if (i < 2048) ((int*)(st + EBO))[i] = 0;
}

// ---------------- q0 = h0_layer0 @ Wq^T ----------------
__global__ __launch_bounds__(256)
void qproj(const float* __restrict__ h0, const float* __restrict__ Wq, float* __restrict__ st) {
  __shared__ float hr[512];
  const int b = blockIdx.x >> 2, o = (blockIdx.x & 3) * 256 + threadIdx.x;
  for (int i = threadIdx.x; i < 512; i += 256) hr[i] = h0[b * 512 + i];
  __syncthreads();
  float acc = 0.f;
  for (int k = 0; k < 512; k += 4) {
    float4 wv = *(const float4*)(&Wq[(long)o * 512 + k]);
    acc += hr[k] * wv.x + hr[k + 1] * wv.y + hr[k + 2] * wv.z + hr[k + 3] * wv.w;
  }
  st[QO + b * 1024 + o] = acc;
}

// ---------------- two-level epoch grid barrier ----------------
// layout (ints): grpCnt[g] at 16*g (g=0..31); rootCnt at 512; grpFlag[g] at 528+16*g.
// 512 blocks = 32 groups x 16. Only 16 arrivals RMW per counter line; only 16
// pollers per flag line at ~0.2us intervals -> no coherence-point storm.
__device__ __forceinline__ void gbar(int* bar, int epoch) {
  __syncthreads();
  if (threadIdx.x == 0) {
    const int g = blockIdx.x >> 4;
    __threadfence();
    int old = __hip_atomic_fetch_add(&bar[g * 16], 1, __ATOMIC_ACQ_REL, __HIP_MEMORY_SCOPE_AGENT);
    if (old == 15) {
      int rold = __hip_atomic_fetch_add(&bar[512], 1, __ATOMIC_ACQ_REL, __HIP_MEMORY_SCOPE_AGENT);
      if (rold == 31) {
        // last block grid-wide: reset counters, then release all groups
        __hip_atomic_store(&bar[512], 0, __ATOMIC_RELAXED, __HIP_MEMORY_SCOPE_AGENT);
#pragma unroll
        for (int gg = 0; gg < 32; ++gg)
          __hip_atomic_store(&bar[gg * 16], 0, __ATOMIC_RELAXED, __HIP_MEMORY_SCOPE_AGENT);
#pragma unroll
        for (int gg = 0; gg < 32; ++gg)
          __hip_atomic_store(&bar[528 + gg * 16], epoch, __ATOMIC_RELEASE, __HIP_MEMORY_SCOPE_AGENT);
      }
    }
    while (__hip_atomic_load(&bar[528 + g * 16], __ATOMIC_ACQUIRE, __HIP_MEMORY_SCOPE_AGENT) < epoch)
      __builtin_amdgcn_s_sleep(8);
    __threadfence();
  }
  __syncthreads();
}

// ---------------- fc: y_hat = relu(h1 @ fc_w^T + b); out + y update ----------------
__device__ void fc_do(const float* __restrict__ fcw, const float* __restrict__ fcb,
                      float* __restrict__ st, float* __restrict__ out,
                      int b, int srow, int hp, int tid, int wv, int ln, float* sm) {
  float* h1s = sm;
  for (int i = tid; i < 512; i += 256) h1s[i] = st[H1O + hp * 16384 + b * 512 + i];
  __syncthreads();
  for (int oi = 0; oi < 32; ++oi) {
    const int o = wv * 32 + oi;
    float part = 0.f;
#pragma unroll
    for (int kk = 0; kk < 8; ++kk) {
      int k = kk * 64 + ln;
      part += h1s[k] * fcw[(long)o * 512 + k];
    }
    for (int off = 32; off; off >>= 1) part += __shfl_down(part, off);
    if (ln == 0) {
      float yh = fmaxf(part + fcb[o], 0.f);
      out[((long)b * SD + srow) * 128 + o] = yh;
      st[YO + b * 128 + o] = 1.f + yh;
    }
  }
  __syncthreads();
}

// ---------------- tier-1 persistent decode: all 128 steps, 4 grid barriers each ----------------
__global__ __launch_bounds__(256, 2)
void decode_all(const u16* __restrict__ key, const u16* __restrict__ value,
                const float* __restrict__ We, const float* __restrict__ Wq,
                const float* __restrict__ wih0, const float* __restrict__ whh0,
                const float* __restrict__ bih0, const float* __restrict__ bhh0,
                const float* __restrict__ wih1, const float* __restrict__ whh1,
                const float* __restrict__ bih1, const float* __restrict__ bhh1,
                const float* __restrict__ fcw, const float* __restrict__ fcb,
                float* __restrict__ st, float* __restrict__ out) {
  __shared__ float sm[5792];
  int* bar = (int*)(st + EBO);
  const int bid = blockIdx.x, tid = threadIdx.x;
  const int wv = tid >> 6, ln = tid & 63;
  int ep = 0;

  for (int s = 0; s < SD; ++s) {
    const int p = s & 1;

    // ---- A: scores (512 blocks = 32 b x 16 t-chunks), pairwise-unrolled for MLP ----
    {
      const int b = bid >> 4, tc = bid & 15, t0 = tc * 32;
      float qr[16], wer[16];
      const float* qp = st + QO + b * 1024 + ln * 16;
#pragma unroll
      for (int j = 0; j < 16; ++j) qr[j] = qp[j];
#pragma unroll
      for (int j = 0; j < 16; j += 4) {
        float4 w4 = *(const float4*)(&We[ln * 16 + j]);
        wer[j] = w4.x; wer[j + 1] = w4.y; wer[j + 2] = w4.z; wer[j + 3] = w4.w;
      }
      const u16* kbase = key + ((long)(b * TE + t0) << 10) + ln * 16;
#pragma unroll
      for (int u = 0; u < 4; ++u) {
        const int tt0 = wv + u * 8, tt1 = wv + u * 8 + 4;
        const u16* kr0 = kbase + ((long)tt0 << 10);
        const u16* kr1 = kbase + ((long)tt1 << 10);
        u16x8 a0 = *(const u16x8*)kr0, a1 = *(const u16x8*)(kr0 + 8);
        u16x8 b0 = *(const u16x8*)kr1, b1 = *(const u16x8*)(kr1 + 8);
        float p0 = 0.f, p1 = 0.f;
#pragma unroll
        for (int j = 0; j < 8; ++j) {
          p0 += tanh_f(qr[j] + b2f(a0[j])) * wer[j];
          p1 += tanh_f(qr[j] + b2f(b0[j])) * wer[j];
        }
#pragma unroll
        for (int j = 0; j < 8; ++j) {
          p0 += tanh_f(qr[8 + j] + b2f(a1[j])) * wer[8 + j];
          p1 += tanh_f(qr[8 + j] + b2f(b1[j])) * wer[8 + j];
        }
        for (int off = 32; off; off >>= 1) {
          p0 += __shfl_down(p0, off);
          p1 += __shfl_down(p1, off);
        }
        if (ln == 0) {
          st[SCO + b * 512 + t0 + tt0] = p0;
          st[SCO + b * 512 + t0 + tt1] = p1;
        }
      }
    }
    gbar(bar, ++ep);

    // ---- B: softmax + ctx = alpha @ value (blocks 0-255) ; fc(s-1) (blocks 256-287) ----
    if (bid < 256) {
      const int b = bid >> 3, dc = bid & 7;
      float* al = sm; float* rr = sm + 512; float* gp = sm + 520;
      al[tid]       = st[SCO + b * 512 + tid];
      al[tid + 256] = st[SCO + b * 512 + tid + 256];
      __syncthreads();
      float m = fmaxf(al[tid], al[tid + 256]);
      for (int off = 32; off; off >>= 1) m = fmaxf(m, __shfl_xor(m, off));
      if (ln == 0) rr[wv] = m;
      __syncthreads();
      const float M = fmaxf(fmaxf(rr[0], rr[1]), fmaxf(rr[2], rr[3]));
      float e0 = __expf(al[tid] - M), e1 = __expf(al[tid + 256] - M);
      float l = e0 + e1;
      for (int off = 32; off; off >>= 1) l += __shfl_xor(l, off);
      if (ln == 0) rr[4 + wv] = l;
      __syncthreads();
      const float inv = __fdividef(1.f, rr[4] + rr[5] + rr[6] + rr[7]);
      al[tid] = e0; al[tid + 256] = e1;
      __syncthreads();
      const int dl = (tid & 31) * 4, tg = tid >> 5;
      float a0 = 0.f, a1 = 0.f, a2 = 0.f, a3 = 0.f;
      const u16* vb = value + ((long)(b * TE) << 10) + dc * 128 + dl;
#pragma unroll 4
      for (int t = tg; t < 512; t += 8) {
        u16x4 vvv = *(const u16x4*)(vb + ((long)t << 10));
        float av = al[t];
        a0 += av * b2f(vvv[0]); a1 += av * b2f(vvv[1]);
        a2 += av * b2f(vvv[2]); a3 += av * b2f(vvv[3]);
      }
      float4 a4 = {a0, a1, a2, a3};
      *(float4*)(&gp[tg * 132 + dl]) = a4;
      __syncthreads();
      if (tid < 128) {
        float ssum = 0.f;
#pragma unroll
        for (int g = 0; g < 8; ++g) ssum += gp[g * 132 + tid];
        st[CTXO + b * 1024 + dc * 128 + tid] = ssum * inv;
      }
    } else if (bid < 288) {
      if (s > 0) fc_do(fcw, fcb, st, out, bid - 256, s - 1, p, tid, wv, ln, sm);
    }
    gbar(bar, ++ep);

    // ---- C: LSTM0 (512 blocks, block = h-dim) ----
    {
      const int h = bid;
      float* xs = sm; float* wr = sm + 4224; float* gp = sm + 4752;
      float acc[4] = {0.f, 0.f, 0.f, 0.f};
      for (int ch = 0; ch < 13; ++ch) {
        const float* src; int stride, col0;
        if (ch == 0)      { src = st + YO;               stride = 128;  col0 = 0; }
        else if (ch <= 8) { src = st + CTXO;             stride = 1024; col0 = (ch - 1) * 128; }
        else              { src = st + H0O + p * 16384;  stride = 512;  col0 = (ch - 9) * 128; }
#pragma unroll
        for (int i = 0; i < 4; ++i) {
          int e4 = tid * 4 + i * 1024;
          int bs = e4 >> 7, j = e4 & 127;
          *(float4*)(&xs[bs * 132 + j]) = *(const float4*)(src + bs * stride + col0 + j);
        }
        {
          int e = tid * 2, r = e >> 7, j = e & 127;  // 4 rows x 128
          const float* wsrc; long rb;
          if (ch <= 8) { wsrc = wih0; rb = (long)(r * 512 + h) * 1152 + ch * 128; }
          else         { wsrc = whh0; rb = (long)(r * 512 + h) * 512 + (ch - 9) * 128; }
          *(float2*)(&wr[r * 132 + j]) = *(const float2*)(&wsrc[rb + j]);
        }
        __syncthreads();
        const int b = tid & 31, j0 = (tid >> 5) * 16;
#pragma unroll
        for (int jj = 0; jj < 16; jj += 4) {
          const float4 xv = *(const float4*)(&xs[b * 132 + j0 + jj]);
#pragma unroll
          for (int r = 0; r < 4; ++r) {
            const float4 w4 = *(const float4*)(&wr[r * 132 + j0 + jj]);
            acc[r] += xv.x * w4.x + xv.y * w4.y + xv.z * w4.z + xv.w * w4.w;
          }
        }
        __syncthreads();
      }
#pragma unroll
      for (int r = 0; r < 4; ++r) acc[r] += __shfl_down(acc[r], 32);
      if (ln < 32) {
#pragma unroll
        for (int r = 0; r < 4; ++r) gp[(wv * 32 + ln) * 4 + r] = acc[r];
      }
      __syncthreads();
      if (tid < 32) {
        const int b = tid;
        float gg[4];
#pragma unroll
        for (int g = 0; g < 4; ++g)
          gg[g] = gp[(0 * 32 + b) * 4 + g] + gp[(1 * 32 + b) * 4 + g] +
                  gp[(2 * 32 + b) * 4 + g] + gp[(3 * 32 + b) * 4 + g] +
                  bih0[g * 512 + h] + bhh0[g * 512 + h];
        float ig = sigm(gg[0]), fg = sigm(gg[1]), gt = tanh_f(gg[2]), og = sigm(gg[3]);
        int si = b * 512 + h;
        float c  = st[C0O + p * 16384 + si];
        float cn = fg * c + ig * gt;
        float hn = og * tanh_f(cn);
        st[H0O + (p ^ 1) * 16384 + si] = hn;
        st[C0O + (p ^ 1) * 16384 + si] = cn;
      }
      __syncthreads();
    }
    gbar(bar, ++ep);

    // ---- D: LSTM1 + q_next (512 blocks, block = h-dim, 2 q-rows) ----
    {
      const int h = bid;
      float* xs = sm; float* wr = sm + 4224; float* gp = sm + 5016;
      float acc[6] = {0.f, 0.f, 0.f, 0.f, 0.f, 0.f};
      for (int ch = 0; ch < 8; ++ch) {
        const float* src = (ch < 4) ? (st + H0O + (p ^ 1) * 16384) : (st + H1O + p * 16384);
        const int col0 = (ch & 3) * 128;
#pragma unroll
        for (int i = 0; i < 4; ++i) {
          int e4 = tid * 4 + i * 1024;
          int bs = e4 >> 7, j = e4 & 127;
          *(float4*)(&xs[bs * 132 + j]) = *(const float4*)(src + bs * 512 + col0 + j);
        }
        {
          int e = tid * 2, r = e >> 7, j = e & 127;
          const float* wsrc = (ch < 4) ? wih1 : whh1;
          long rb = (long)(r * 512 + h) * 512 + col0;
          *(float2*)(&wr[r * 132 + j]) = *(const float2*)(&wsrc[rb + j]);
          if (ch < 4) {
            int rq = tid >> 7, j2 = tid & 127;  // 2 rows x 128
            wr[(4 + rq) * 132 + j2] = Wq[(long)(2 * h + rq) * 512 + col0 + j2];
          }
        }
        __syncthreads();
        const int b = tid & 31, j0 = (tid >> 5) * 16;
#pragma unroll
        for (int jj = 0; jj < 16; jj += 4) {
          const float4 xv = *(const float4*)(&xs[b * 132 + j0 + jj]);
#pragma unroll
          for (int r = 0; r < 4; ++r) {
            const float4 w4 = *(const float4*)(&wr[r * 132 + j0 + jj]);
            acc[r] += xv.x * w4.x + xv.y * w4.y + xv.z * w4.z + xv.w * w4.w;
          }
          if (ch < 4) {
#pragma unroll
            for (int r = 4; r < 6; ++r) {
              const float4 w4 = *(const float4*)(&wr[r * 132 + j0 + jj]);
              acc[r] += xv.x * w4.x + xv.y * w4.y + xv.z * w4.z + xv.w * w4.w;
            }
          }
        }
        __syncthreads();
      }
#pragma unroll
      for (int r = 0; r < 6; ++r) acc[r] += __shfl_down(acc[r], 32);
      if (ln < 32) {
#pragma unroll
        for (int r = 0; r < 6; ++r) gp[(wv * 32 + ln) * 6 + r] = acc[r];
      }
      __syncthreads();
      if (tid < 32) {
        const int b = tid;
        float gg[4];
#pragma unroll
        for (int g = 0; g < 4; ++g)
          gg[g] = gp[(0 * 32 + b) * 6 + g] + gp[(1 * 32 + b) * 6 + g] +
                  gp[(2 * 32 + b) * 6 + g] + gp[(3 * 32 + b) * 6 + g] +
                  bih1[g * 512 + h] + bhh1[g * 512 + h];
        float ig = sigm(gg[0]), fg = sigm(gg[1]), gt = tanh_f(gg[2]), og = sigm(gg[3]);
        int si = b * 512 + h;
        float c  = st[C1O + p * 16384 + si];
        float cn = fg * c + ig * gt;
        float hn = og * tanh_f(cn);
        st[H1O + (p ^ 1) * 16384 + si] = hn;
        st[C1O + (p ^ 1) * 16384 + si] = cn;
        float q0 = gp[(0 * 32 + b) * 6 + 4] + gp[(1 * 32 + b) * 6 + 4] +
                   gp[(2 * 32 + b) * 6 + 4] + gp[(3 * 32 + b) * 6 + 4];
        float q1 = gp[(0 * 32 + b) * 6 + 5] + gp[(1 * 32 + b) * 6 + 5] +
                   gp[(2 * 32 + b) * 6 + 5] + gp[(3 * 32 + b) * 6 + 5];
        st[QO + b * 1024 + 2 * h]     = q0;
        st[QO + b * 1024 + 2 * h + 1] = q1;
      }
      __syncthreads();
    }
    gbar(bar, ++ep);
  }

  // final fc for step SD-1 (h1[127] at parity 0)
  if (bid >= 256 && bid < 288)
    fc_do(fcw, fcb, st, out, bid - 256, SD - 1, 0, tid, wv, ln, sm);
}

// ================= tier-2 fallback (round-4 proven path, bf16 key) =================
__global__ __launch_bounds__(256)
void stepA2(const u16* __restrict__ key, const float* __restrict__ We, float* __restrict__ st) {
  const int tid = threadIdx.x, wv = tid >> 6, ln = tid & 63;
  const int b = blockIdx.x >> 4, tc = blockIdx.x & 15, t0 = tc * 32;
  float qr[16], wer[16];
  {
    const float* qp = st + QO + b * 1024 + ln * 16;
#pragma unroll
    for (int j = 0; j < 16; ++j) qr[j] = qp[j];
#pragma unroll
    for (int j = 0; j < 16; j += 4) {
      float4 w4 = *(const float4*)(&We[ln * 16 + j]);
      wer[j] = w4.x; wer[j + 1] = w4.y; wer[j + 2] = w4.z; wer[j + 3] = w4.w;
    }
  }
  for (int tt = wv; tt < 32; tt += 4) {
    const u16* kr = key + ((long)(b * TE + t0 + tt) << 10) + ln * 16;
    u16x8 k0 = *(const u16x8*)kr, k1 = *(const u16x8*)(kr + 8);
    float part = 0.f;
#pragma unroll
    for (int j = 0; j < 8; ++j) part += tanh_f(qr[j] + b2f(k0[j])) * wer[j];
#pragma unroll
    for (int j = 0; j < 8; ++j) part += tanh_f(qr[8 + j] + b2f(k1[j])) * wer[8 + j];
    for (int off = 32; off; off >>= 1) part += __shfl_down(part, off);
    if (ln == 0) st[SCO + b * 512 + t0 + tt] = part;
  }
}

__global__ __launch_bounds__(256)
void stepB2(const float* __restrict__ E, float* __restrict__ st) {
  __shared__ float al[512];
  __shared__ float rr[8];
  __shared__ float gp[8 * 132];
  const int tid = threadIdx.x, wv = tid >> 6, ln = tid & 63;
  const int b = blockIdx.x >> 3, dc = blockIdx.x & 7;
  al[tid]       = st[SCO + b * 512 + tid];
  al[tid + 256] = st[SCO + b * 512 + tid + 256];
  __syncthreads();
  float m = fmaxf(al[tid], al[tid + 256]);
  for (int off = 32; off; off >>= 1) m = fmaxf(m, __shfl_xor(m, off));
  if (ln == 0) rr[wv] = m;
  __syncthreads();
  const float M = fmaxf(fmaxf(rr[0], rr[1]), fmaxf(rr[2], rr[3]));
  float e0 = __expf(al[tid] - M), e1 = __expf(al[tid + 256] - M);
  float l = e0 + e1;
  for (int off = 32; off; off >>= 1) l += __shfl_xor(l, off);
  if (ln == 0) rr[4 + wv] = l;
  __syncthreads();
  const float inv = __fdividef(1.f, rr[4] + rr[5] + rr[6] + rr[7]);
  al[tid] = e0; al[tid + 256] = e1;
  __syncthreads();
  const int dl = (tid & 31) * 4;
  const int tg = tid >> 5;
  float a0 = 0.f, a1 = 0.f, a2 = 0.f, a3 = 0.f;
  const float* Eb = E + ((long)b * TE) * 1024 + dc * 128 + dl;
  for (int t = tg; t < 512; t += 8) {
    float4 ev = *(const float4*)(Eb + (long)t * 1024);
    float av = al[t];
    a0 += av * ev.x; a1 += av * ev.y; a2 += av * ev.z; a3 += av * ev.w;
  }
  float4 av4 = {a0, a1, a2, a3};
  *(float4*)(&gp[tg * 132 + dl]) = av4;
  __syncthreads();
  if (tid < 128) {
    float s = 0.f;
#pragma unroll
    for (int g = 0; g < 8; ++g) s += gp[g * 132 + tid];
    st[EBO + b * 1024 + dc * 128 + tid] = s * inv;
  }
}

__global__ __launch_bounds__(256)
void stepC2(const float* __restrict__ Wv, const float* __restrict__ fcw,
            const float* __restrict__ fcb, float* __restrict__ st,
            float* __restrict__ out, int s) {
  const int tid = threadIdx.x, wv = tid >> 6, ln = tid & 63;
  if (blockIdx.x < 64) {
    __shared__ float ebs[32 * 132];
    __shared__ float wvs[16 * 132];
    const int och = blockIdx.x * 16;
    const int o = tid >> 4;
    const int b0 = (tid & 15) * 2;
    float acc0 = 0.f, acc1 = 0.f;
    for (int dch = 0; dch < 8; ++dch) {
#pragma unroll
      for (int i = 0; i < 4; ++i) {
        int idx = tid * 4 + i * 1024;
        int bb = idx >> 7, dd = idx & 127;
        *(float4*)(&ebs[bb * 132 + dd]) = *(const float4*)(st + EBO + bb * 1024 + dch * 128 + dd);
      }
      {
        int r = tid >> 4, c = (tid & 15) * 8;
        const float* wp = &Wv[(long)(och + r) * 1024 + dch * 128 + c];
        *(float4*)(&wvs[r * 132 + c])     = *(const float4*)wp;
        *(float4*)(&wvs[r * 132 + c + 4]) = *(const float4*)(wp + 4);
      }
      __syncthreads();
#pragma unroll
      for (int j = 0; j < 128; j += 4) {
        float4 w4 = *(const float4*)(&wvs[o * 132 + j]);
        float4 x0 = *(const float4*)(&ebs[b0 * 132 + j]);
        float4 x1 = *(const float4*)(&ebs[(b0 + 1) * 132 + j]);
        acc0 += x0.x * w4.x + x0.y * w4.y + x0.z * w4.z + x0.w * w4.w;
        acc1 += x1.x * w4.x + x1.y * w4.y + x1.z * w4.z + x1.w * w4.w;
      }
      __syncthreads();
    }
    st[CTXO + b0 * 1024 + och + o]       = acc0;
    st[CTXO + (b0 + 1) * 1024 + och + o] = acc1;
  } else if (s > 0) {
    __shared__ float h1s[512];
    const int b = blockIdx.x - 64;
    const int p = s & 1;
    for (int i = tid; i < 512; i += 256) h1s[i] = st[H1O + p * 16384 + b * 512 + i];
    __syncthreads();
#pragma unroll
    for (int oi = 0; oi < 32; ++oi) {
      const int o = wv * 32 + oi;
      float part = 0.f;
#pragma unroll
      for (int kk = 0; kk < 8; ++kk) {
        int k = kk * 64 + ln;
        part += h1s[k] * fcw[(long)o * 512 + k];
      }
      for (int off = 32; off; off >>= 1) part += __shfl_down(part, off);
      if (ln == 0) {
        float yh = fmaxf(part + fcb[o], 0.f);
        out[((long)b * SD + (s - 1)) * 128 + o] = yh;
        st[YO + b * 128 + o] = 1.f + yh;
      }
    }
  }
}

__global__ __launch_bounds__(256)
void stepD2(const float* __restrict__ wih0, const float* __restrict__ whh0,
            const float* __restrict__ bih0, const float* __restrict__ bhh0,
            float* __restrict__ st, int p) {
  __shared__ float xs[32 * 132];
  __shared__ float wr[8 * 132];
  __shared__ float gp[4 * 32 * 8];
  const int tid = threadIdx.x, wv = tid >> 6, ln = tid & 63;
  const int h0d = blockIdx.x * 2;
  float acc[8];
#pragma unroll
  for (int r = 0; r < 8; ++r) acc[r] = 0.f;
  for (int ch = 0; ch < 13; ++ch) {
    const float* src; int stride, col0;
    if (ch == 0)      { src = st + YO;               stride = 128;  col0 = 0; }
    else if (ch <= 8) { src = st + CTXO;             stride = 1024; col0 = (ch - 1) * 128; }
    else              { src = st + H0O + p * 16384;  stride = 512;  col0 = (ch - 9) * 128; }
#pragma unroll
    for (int i = 0; i < 4; ++i) {
      int e4 = tid * 4 + i * 1024;
      int bs = e4 >> 7, j = e4 & 127;
      *(float4*)(&xs[bs * 132 + j]) = *(const float4*)(src + bs * stride + col0 + j);
    }
    {
      int e = tid * 4, r = e >> 7, j = e & 127;
      int g = r >> 1, hh = r & 1;
      const float* wsrc; long rb;
      if (ch <= 8) { wsrc = wih0; rb = (long)(g * 512 + h0d + hh) * 1152 + ch * 128; }
      else         { wsrc = whh0; rb = (long)(g * 512 + h0d + hh) * 512 + (ch - 9) * 128; }
      *(float4*)(&wr[r * 132 + j]) = *(const float4*)(&wsrc[rb + j]);
    }
    __syncthreads();
    const int b = tid & 31, j0 = (tid >> 5) * 16;
#pragma unroll
    for (int jj = 0; jj < 16; jj += 4) {
      const float4 xv = *(const float4*)(&xs[b * 132 + j0 + jj]);
#pragma unroll
      for (int r = 0; r < 8; ++r) {
        const float4 w4 = *(const float4*)(&wr[r * 132 + j0 + jj]);
        acc[r] += xv.x * w4.x + xv.y * w4.y + xv.z * w4.z + xv.w * w4.w;
      }
    }
    __syncthreads();
  }
#pragma unroll
  for (int r = 0; r < 8; ++r) acc[r] += __shfl_down(acc[r], 32);
  if (ln < 32) {
#pragma unroll
    for (int r = 0; r < 8; ++r) gp[(wv * 32 + ln) * 8 + r] = acc[r];
  }
  __syncthreads();
  if (tid < 64) {
    const int b = tid & 31, hh = tid >> 5, h = h0d + hh;
    float gg[4];
#pragma unroll
    for (int g = 0; g < 4; ++g) {
      int r = g * 2 + hh;
      gg[g] = gp[(0 * 32 + b) * 8 + r] + gp[(1 * 32 + b) * 8 + r] +
              gp[(2 * 32 + b) * 8 + r] + gp[(3 * 32 + b) * 8 + r] +
              bih0[g * 512 + h] + bhh0[g * 512 + h];
    }
    float ig = sigm(gg[0]), fg = sigm(gg[1]), gt = tanh_f(gg[2]), og = sigm(gg[3]);
    int si = b * 512 + h;
    float c  = st[C0O + p * 16384 + si];
    float cn = fg * c + ig * gt;
    float hn = og * tanh_f(cn);
    st[H0O + (p ^ 1) * 16384 + si] = hn;
    st[C0O + (p ^ 1) * 16384 + si] = cn;
  }
}

__global__ __launch_bounds__(256)
void stepE2(const float* __restrict__ wih1, const float* __restrict__ whh1,
            const float* __restrict__ bih1, const float* __restrict__ bhh1,
            const float* __restrict__ Wq, float* __restrict__ st, int p) {
  __shared__ float xs[32 * 132];
  __shared__ float wr[12 * 132];
  __shared__ float gp[4 * 32 * 12];
  const int tid = threadIdx.x, wv = tid >> 6, ln = tid & 63;
  const int h0d = blockIdx.x * 2;
  float acc[12];
#pragma unroll
  for (int r = 0; r < 12; ++r) acc[r] = 0.f;
  for (int ch = 0; ch < 8; ++ch) {
    const float* src = (ch < 4) ? (st + H0O + (p ^ 1) * 16384) : (st + H1O + p * 16384);
    const int col0 = (ch & 3) * 128;
#pragma unroll
    for (int i = 0; i < 4; ++i) {
      int e4 = tid * 4 + i * 1024;
      int bs = e4 >> 7, j = e4 & 127;
      *(float4*)(&xs[bs * 132 + j]) = *(const float4*)(src + bs * 512 + col0 + j);
    }
    {
      int e = tid * 4, r = e >> 7, j = e & 127;
      int g = r >> 1, hh = r & 1;
      const float* wsrc = (ch < 4) ? wih1 : whh1;
      long rb = (long)(g * 512 + h0d + hh) * 512 + col0;
      *(float4*)(&wr[r * 132 + j]) = *(const float4*)(&wsrc[rb + j]);
      if (ch < 4 && tid < 128) {
        int rq = e >> 7, j2 = e & 127;
        long rqb = (long)(4 * blockIdx.x + rq) * 512 + col0;
        *(float4*)(&wr[(8 + rq) * 132 + j2]) = *(const float4*)(&Wq[rqb + j2]);
      }
    }
    __syncthreads();
    const int b = tid & 31, j0 = (tid >> 5) * 16;
#pragma unroll
    for (int jj = 0; jj < 16; jj += 4) {
      const float4 xv = *(const float4*)(&xs[b * 132 + j0 + jj]);
#pragma unroll
      for (int r = 0; r < 8; ++r) {
        const float4 w4 = *(const float4*)(&wr[r * 132 + j0 + jj]);
        acc[r] += xv.x * w4.x + xv.y * w4.y + xv.z * w4.z + xv.w * w4.w;
      }
      if (ch < 4) {
#pragma unroll
        for (int r = 8; r < 12; ++r) {
          const float4 w4 = *(const float4*)(&wr[r * 132 + j0 + jj]);
          acc[r] += xv.x * w4.x + xv.y * w4.y + xv.z * w4.z + xv.w * w4.w;
        }
      }
    }
    __syncthreads();
  }
#pragma unroll
  for (int r = 0; r < 12; ++r) acc[r] += __shfl_down(acc[r], 32);
  if (ln < 32) {
#pragma unroll
    for (int r = 0; r < 12; ++r) gp[(wv * 32 + ln) * 12 + r] = acc[r];
  }
  __syncthreads();
  if (tid < 64) {
    const int b = tid & 31, hh = tid >> 5, h = h0d + hh;
    float gg[4];
#pragma unroll
    for (int g = 0; g < 4; ++g) {
      int r = g * 2 + hh;
      gg[g] = gp[(0 * 32 + b) * 12 + r] + gp[(1 * 32 + b) * 12 + r] +
              gp[(2 * 32 + b) * 12 + r] + gp[(3 * 32 + b) * 12 + r] +
              bih1[g * 512 + h] + bhh1[g * 512 + h];
    }
    float ig = sigm(gg[0]), fg = sigm(gg[1]), gt = tanh_f(gg[2]), og = sigm(gg[3]);
    int si = b * 512 + h;
    float c  = st[C1O + p * 16384 + si];
    float cn = fg * c + ig * gt;
    float hn = og * tanh_f(cn);
    st[H1O + (p ^ 1) * 16384 + si] = hn;
    st[C1O + (p ^ 1) * 16384 + si] = cn;
    int r0 = 8 + 2 * hh;
    float q0 = gp[(0 * 32 + b) * 12 + r0]     + gp[(1 * 32 + b) * 12 + r0] +
               gp[(2 * 32 + b) * 12 + r0]     + gp[(3 * 32 + b) * 12 + r0];
    float q1 = gp[(0 * 32 + b) * 12 + r0 + 1] + gp[(1 * 32 + b) * 12 + r0 + 1] +
               gp[(2 * 32 + b) * 12 + r0 + 1] + gp[(3 * 32 + b) * 12 + r0 + 1];
    int o0 = 4 * blockIdx.x + 2 * hh;
    st[QO + b * 1024 + o0]     = q0;
    st[QO + b * 1024 + o0 + 1] = q1;
  }
}

__global__ __launch_bounds__(256)
void fcK2(const float* __restrict__ fcw, const float* __restrict__ fcb,
          float* __restrict__ st, float* __restrict__ out) {
  __shared__ float h1s[512];
  const int b = blockIdx.x >> 2, og = (blockIdx.x & 3) * 32;
  const int tid = threadIdx.x, wv = tid >> 6, ln = tid & 63;
  for (int i = tid; i < 512; i += 256) h1s[i] = st[H1O + b * 512 + i];
  __syncthreads();
#pragma unroll
  for (int oi = 0; oi < 8; ++oi) {
    const int o = og + wv * 8 + oi;
    float part = 0.f;
#pragma unroll
    for (int kk = 0; kk < 8; ++kk) {
      int k = kk * 64 + ln;
      part += h1s[k] * fcw[(long)o * 512 + k];
    }
    for (int off = 32; off; off >>= 1) part += __shfl_down(part, off);
    if (ln == 0) {
      float yh = fmaxf(part + fcb[o], 0.f);
      out[((long)b * SD + (SD - 1)) * 128 + o] = yh;
    }
  }
}

extern "C" void kernel_launch(void* const* d_in, const int* in_sizes, int n_in,
                              void* d_out, int out_size, void* d_ws, size_t ws_size,
                              hipStream_t stream) {
  (void)in_sizes; (void)n_in; (void)out_size;
  float* out = (float*)d_out;

  const float* E    = (const float*)d_in[0];
  const float* h0   = (const float*)d_in[1];
  const float* c0   = (const float*)d_in[2];
  const float* Wk   = (const float*)d_in[3];
  const float* Wq   = (const float*)d_in[4];
  const float* Wv   = (const float*)d_in[5];
  const float* We   = (const float*)d_in[6];
  const float* wih0 = (const float*)d_in[7];
  const float* whh0 = (const float*)d_in[8];
  const float* bih0 = (const float*)d_in[9];
  const float* bhh0 = (const float*)d_in[10];
  const float* wih1 = (const float*)d_in[11];
  const float* whh1 = (const float*)d_in[12];
  const float* bih1 = (const float*)d_in[13];
  const float* bhh1 = (const float*)d_in[14];
  const float* fcw  = (const float*)d_in[15];
  const float* fcb  = (const float*)d_in[16];

  // tier1: bf16 key (33.5MB) + bf16 value (33.5MB) + state (~1MB)
  const bool tier1 = ws_size >= (size_t)(16777216ull * 4 + ST_N * 4 + 4096);

  if (tier1) {
    u16* key   = (u16*)d_ws;
    u16* value = key + 16777216;
    float* st  = (float*)d_ws + 16777216;   // byte 67,108,864
    gemm_nt<<<dim3(256, 16), 256, 0, stream>>>(E, Wk, key);
    gemm_nt<<<dim3(256, 16), 256, 0, stream>>>(E, Wv, value);
    init_state<<<64, 256, 0, stream>>>(h0, c0, st);
    qproj<<<128, 256, 0, stream>>>(h0, Wq, st);
    decode_all<<<NB, 256, 0, stream>>>(key, value, We, Wq, wih0, whh0, bih0, bhh0,
                                       wih1, whh1, bih1, bhh1, fcw, fcb, st, out);
  } else {
    u16* key  = (u16*)d_ws;
    float* st = (float*)d_ws + 8388608;     // byte 33,554,432 (round-4 proven)
    gemm_nt<<<dim3(256, 16), 256, 0, stream>>>(E, Wk, key);
    init_state<<<64, 256, 0, stream>>>(h0, c0, st);
    qproj<<<128, 256, 0, stream>>>(h0, Wq, st);
    for (int s = 0; s < SD; ++s) {
      int p = s & 1;
      stepA2<<<512, 256, 0, stream>>>(key, We, st);
      stepB2<<<256, 256, 0, stream>>>(E, st);
      stepC2<<<96, 256, 0, stream>>>(Wv, fcw, fcb, st, out, s);
      stepD2<<<256, 256, 0, stream>>>(wih0, whh0, bih0, bhh0, st, p);
      stepE2<<<256, 256, 0, stream>>>(wih1, whh1, bih1, bhh1, Wq, st, p);
    }
    fcK2<<<128, 256, 0, stream>>>(fcw, fcb, st, out);
  }
}

// Round 7
// 12082.910 us; speedup vs baseline: 10.7249x; 10.7249x over previous
//
#include <hip/hip_runtime.h>
#include <hip/hip_bf16.h>
#include <cstdint>

// Problem dims
#define TE    512
#define SD    128

typedef unsigned short u16;
typedef u16 u16x4 __attribute__((ext_vector_type(4)));
typedef u16 u16x8 __attribute__((ext_vector_type(8)));

// State region offsets (floats), relative to st pointer (st = d_ws + 67,108,864 B;
// rounds 5/6 proved ws_size >= 68.1 MB)
#define QO    0          // [32][1024]
#define SCO   32768      // [32][512]
#define CTXO  81920      // [32][1024]
#define YO    114688     // [32][128]
#define H0O   118784     // [2][32][512]
#define C0O   151552
#define H1O   184320
#define C1O   217088
#define ST_N  249856

__device__ __forceinline__ float b2f(u16 v) { return __uint_as_float(((unsigned)v) << 16); }
__device__ __forceinline__ u16 f2b(float f) {
  unsigned u = __float_as_uint(f);
  return (u16)((u + 0x7FFFu + ((u >> 16) & 1u)) >> 16);
}
__device__ __forceinline__ float tanh_f(float x) {
  float xc = fminf(12.f, fmaxf(-12.f, x));
  float e  = __expf(2.f * xc);
  return __fdividef(e - 1.f, e + 1.f);
}
__device__ __forceinline__ float sigm(float x) {
  float xc = fminf(30.f, fmaxf(-30.f, x));
  return __fdividef(1.f, 1.f + __expf(-xc));
}

// ---------------- NT GEMM: key=E@Wk^T, value=E@Wv^T (fp32 in, bf16 out) ----------------
__global__ __launch_bounds__(256)
void gemm_kv(const float* __restrict__ E, const float* __restrict__ Wk,
             const float* __restrict__ Wv, u16* __restrict__ key, u16* __restrict__ value) {
  const float* B = blockIdx.z ? Wv : Wk;
  u16* outp = blockIdx.z ? value : key;
  __shared__ float Asm[16][68], Bsm[16][68];
  const int tid = threadIdx.x;
  const int tm = blockIdx.x * 64, tn = blockIdx.y * 64;
  const int lr = tid >> 2, lc = (tid & 3) * 4;
  const int tx = tid & 15, ty = tid >> 4;
  float acc[4][4] = {};
  for (int k0 = 0; k0 < 1024; k0 += 16) {
    float4 av = *(const float4*)(&E[(long)(tm + lr) * 1024 + k0 + lc]);
    float4 bv = *(const float4*)(&B[(long)(tn + lr) * 1024 + k0 + lc]);
    Asm[lc][lr] = av.x; Asm[lc + 1][lr] = av.y; Asm[lc + 2][lr] = av.z; Asm[lc + 3][lr] = av.w;
    Bsm[lc][lr] = bv.x; Bsm[lc + 1][lr] = bv.y; Bsm[lc + 2][lr] = bv.z; Bsm[lc + 3][lr] = bv.w;
    __syncthreads();
#pragma unroll
    for (int kk = 0; kk < 16; ++kk) {
      float4 a4 = *(const float4*)(&Asm[kk][ty * 4]);
      float4 b4 = *(const float4*)(&Bsm[kk][tx * 4]);
      acc[0][0] += a4.x * b4.x; acc[0][1] += a4.x * b4.y; acc[0][2] += a4.x * b4.z; acc[0][3] += a4.x * b4.w;
      acc[1][0] += a4.y * b4.x; acc[1][1] += a4.y * b4.y; acc[1][2] += a4.y * b4.z; acc[1][3] += a4.y * b4.w;
      acc[2][0] += a4.z * b4.x; acc[2][1] += a4.z * b4.y; acc[2][2] += a4.z * b4.z; acc[2][3] += a4.z * b4.w;
      acc[3][0] += a4.w * b4.x; acc[3][1] += a4.w * b4.y; acc[3][2] += a4.w * b4.z; acc[3][3] += a4.w * b4.w;
    }
    __syncthreads();
  }
#pragma unroll
  for (int i = 0; i < 4; ++i)
#pragma unroll
    for (int j = 0; j < 4; ++j)
      outp[(long)(tm + ty * 4 + i) * 1024 + tn + tx * 4 + j] = f2b(acc[i][j]);
}

// ---------------- init: h/c -> parity-0 state, zero y ----------------
__global__ __launch_bounds__(256)
void init_state(const float* __restrict__ h0, const float* __restrict__ c0, float* __restrict__ st) {
  int i = blockIdx.x * 256 + threadIdx.x;   // 16384 threads
  st[H0O + i] = h0[i];
  st[H1O + i] = h0[16384 + i];
  st[C0O + i] = c0[i];
  st[C1O + i] = c0[16384 + i];
  if (i < 4096) st[YO + i] = 0.f;
}

// ---------------- q0 = h0_layer0 @ Wq^T ----------------
__global__ __launch_bounds__(256)
void qproj(const float* __restrict__ h0, const float* __restrict__ Wq, float* __restrict__ st) {
  __shared__ float hr[512];
  const int b = blockIdx.x >> 2, o = (blockIdx.x & 3) * 256 + threadIdx.x;
  for (int i = threadIdx.x; i < 512; i += 256) hr[i] = h0[b * 512 + i];
  __syncthreads();
  float acc = 0.f;
  for (int k = 0; k < 512; k += 4) {
    float4 wv = *(const float4*)(&Wq[(long)o * 512 + k]);
    acc += hr[k] * wv.x + hr[k + 1] * wv.y + hr[k + 2] * wv.z + hr[k + 3] * wv.w;
  }
  st[QO + b * 1024 + o] = acc;
}

// ---------------- step A: raw scores (bf16 key, pairwise-unrolled) ----------------
__global__ __launch_bounds__(256)
void stepA(const u16* __restrict__ key, const float* __restrict__ We, float* __restrict__ st) {
  const int tid = threadIdx.x, wv = tid >> 6, ln = tid & 63;
  const int b = blockIdx.x >> 4, tc = blockIdx.x & 15, t0 = tc * 32;
  float qr[16], wer[16];
  {
    const float* qp = st + QO + b * 1024 + ln * 16;
#pragma unroll
    for (int j = 0; j < 16; ++j) qr[j] = qp[j];
#pragma unroll
    for (int j = 0; j < 16; j += 4) {
      float4 w4 = *(const float4*)(&We[ln * 16 + j]);
      wer[j] = w4.x; wer[j + 1] = w4.y; wer[j + 2] = w4.z; wer[j + 3] = w4.w;
    }
  }
  const u16* kbase = key + ((long)(b * TE + t0) << 10) + ln * 16;
#pragma unroll
  for (int u = 0; u < 4; ++u) {
    const int tt0 = wv + u * 8, tt1 = wv + u * 8 + 4;
    const u16* kr0 = kbase + ((long)tt0 << 10);
    const u16* kr1 = kbase + ((long)tt1 << 10);
    u16x8 a0 = *(const u16x8*)kr0, a1 = *(const u16x8*)(kr0 + 8);
    u16x8 b0 = *(const u16x8*)kr1, b1 = *(const u16x8*)(kr1 + 8);
    float p0 = 0.f, p1 = 0.f;
#pragma unroll
    for (int j = 0; j < 8; ++j) {
      p0 += tanh_f(qr[j] + b2f(a0[j])) * wer[j];
      p1 += tanh_f(qr[j] + b2f(b0[j])) * wer[j];
    }
#pragma unroll
    for (int j = 0; j < 8; ++j) {
      p0 += tanh_f(qr[8 + j] + b2f(a1[j])) * wer[8 + j];
      p1 += tanh_f(qr[8 + j] + b2f(b1[j])) * wer[8 + j];
    }
    for (int off = 32; off; off >>= 1) {
      p0 += __shfl_down(p0, off);
      p1 += __shfl_down(p1, off);
    }
    if (ln == 0) {
      st[SCO + b * 512 + t0 + tt0] = p0;
      st[SCO + b * 512 + t0 + tt1] = p1;
    }
  }
}

// ---------------- step B: softmax + ctx = alpha @ value (blocks 0-255) + fc(s-1) (256-287) ----------------
__global__ __launch_bounds__(256)
void stepB(const u16* __restrict__ value, const float* __restrict__ fcw,
           const float* __restrict__ fcb, float* __restrict__ st,
           float* __restrict__ out, int s) {
  __shared__ float sm[1576];
  const int tid = threadIdx.x, wv = tid >> 6, ln = tid & 63;
  if (blockIdx.x < 256) {
    const int b = blockIdx.x >> 3, dc = blockIdx.x & 7;
    float* al = sm; float* rr = sm + 512; float* gp = sm + 520;
    al[tid]       = st[SCO + b * 512 + tid];
    al[tid + 256] = st[SCO + b * 512 + tid + 256];
    __syncthreads();
    float m = fmaxf(al[tid], al[tid + 256]);
    for (int off = 32; off; off >>= 1) m = fmaxf(m, __shfl_xor(m, off));
    if (ln == 0) rr[wv] = m;
    __syncthreads();
    const float M = fmaxf(fmaxf(rr[0], rr[1]), fmaxf(rr[2], rr[3]));
    float e0 = __expf(al[tid] - M), e1 = __expf(al[tid + 256] - M);
    float l = e0 + e1;
    for (int off = 32; off; off >>= 1) l += __shfl_xor(l, off);
    if (ln == 0) rr[4 + wv] = l;
    __syncthreads();
    const float inv = __fdividef(1.f, rr[4] + rr[5] + rr[6] + rr[7]);
    al[tid] = e0; al[tid + 256] = e1;
    __syncthreads();
    const int dl = (tid & 31) * 4, tg = tid >> 5;
    float a0 = 0.f, a1 = 0.f, a2 = 0.f, a3 = 0.f;
    const u16* vb = value + ((long)(b * TE) << 10) + dc * 128 + dl;
#pragma unroll 4
    for (int t = tg; t < 512; t += 8) {
      u16x4 vvv = *(const u16x4*)(vb + ((long)t << 10));
      float av = al[t];
      a0 += av * b2f(vvv[0]); a1 += av * b2f(vvv[1]);
      a2 += av * b2f(vvv[2]); a3 += av * b2f(vvv[3]);
    }
    float4 a4 = {a0, a1, a2, a3};
    *(float4*)(&gp[tg * 132 + dl]) = a4;
    __syncthreads();
    if (tid < 128) {
      float ssum = 0.f;
#pragma unroll
      for (int g = 0; g < 8; ++g) ssum += gp[g * 132 + tid];
      st[CTXO + b * 1024 + dc * 128 + tid] = ssum * inv;
    }
  } else if (s > 0) {
    // fc for previous step: blocks 256-287, b = bid-256
    float* h1s = sm;
    const int b = blockIdx.x - 256;
    const int p = s & 1;   // h1[s-1] lives at parity s&1
    for (int i = tid; i < 512; i += 256) h1s[i] = st[H1O + p * 16384 + b * 512 + i];
    __syncthreads();
#pragma unroll
    for (int oi = 0; oi < 32; ++oi) {
      const int o = wv * 32 + oi;
      float part = 0.f;
#pragma unroll
      for (int kk = 0; kk < 8; ++kk) {
        int k = kk * 64 + ln;
        part += h1s[k] * fcw[(long)o * 512 + k];
      }
      for (int off = 32; off; off >>= 1) part += __shfl_down(part, off);
      if (ln == 0) {
        float yh = fmaxf(part + fcb[o], 0.f);
        out[((long)b * SD + (s - 1)) * 128 + o] = yh;
        st[YO + b * 128 + o] = 1.f + yh;
      }
    }
  }
}

// ---------------- step C: LSTM0 (block owns 2 h-dims; proven round 4) ----------------
__global__ __launch_bounds__(256)
void stepC(const float* __restrict__ wih0, const float* __restrict__ whh0,
           const float* __restrict__ bih0, const float* __restrict__ bhh0,
           float* __restrict__ st, int p) {
  __shared__ float xs[32 * 132];
  __shared__ float wr[8 * 132];
  __shared__ float gp[4 * 32 * 8];
  const int tid = threadIdx.x, wv = tid >> 6, ln = tid & 63;
  const int h0d = blockIdx.x * 2;
  float acc[8];
#pragma unroll
  for (int r = 0; r < 8; ++r) acc[r] = 0.f;
  for (int ch = 0; ch < 13; ++ch) {
    const float* src; int stride, col0;
    if (ch == 0)      { src = st + YO;               stride = 128;  col0 = 0; }
    else if (ch <= 8) { src = st + CTXO;             stride = 1024; col0 = (ch - 1) * 128; }
    else              { src = st + H0O + p * 16384;  stride = 512;  col0 = (ch - 9) * 128; }
#pragma unroll
    for (int i = 0; i < 4; ++i) {
      int e4 = tid * 4 + i * 1024;
      int bs = e4 >> 7, j = e4 & 127;
      *(float4*)(&xs[bs * 132 + j]) = *(const float4*)(src + bs * stride + col0 + j);
    }
    {
      int e = tid * 4, r = e >> 7, j = e & 127;
      int g = r >> 1, hh = r & 1;
      const float* wsrc; long rb;
      if (ch <= 8) { wsrc = wih0; rb = (long)(g * 512 + h0d + hh) * 1152 + ch * 128; }
      else         { wsrc = whh0; rb = (long)(g * 512 + h0d + hh) * 512 + (ch - 9) * 128; }
      *(float4*)(&wr[r * 132 + j]) = *(const float4*)(&wsrc[rb + j]);
    }
    __syncthreads();
    const int b = tid & 31, j0 = (tid >> 5) * 16;
#pragma unroll
    for (int jj = 0; jj < 16; jj += 4) {
      const float4 xv = *(const float4*)(&xs[b * 132 + j0 + jj]);
#pragma unroll
      for (int r = 0; r < 8; ++r) {
        const float4 w4 = *(const float4*)(&wr[r * 132 + j0 + jj]);
        acc[r] += xv.x * w4.x + xv.y * w4.y + xv.z * w4.z + xv.w * w4.w;
      }
    }
    __syncthreads();
  }
#pragma unroll
  for (int r = 0; r < 8; ++r) acc[r] += __shfl_down(acc[r], 32);
  if (ln < 32) {
#pragma unroll
    for (int r = 0; r < 8; ++r) gp[(wv * 32 + ln) * 8 + r] = acc[r];
  }
  __syncthreads();
  if (tid < 64) {
    const int b = tid & 31, hh = tid >> 5, h = h0d + hh;
    float gg[4];
#pragma unroll
    for (int g = 0; g < 4; ++g) {
      int r = g * 2 + hh;
      gg[g] = gp[(0 * 32 + b) * 8 + r] + gp[(1 * 32 + b) * 8 + r] +
              gp[(2 * 32 + b) * 8 + r] + gp[(3 * 32 + b) * 8 + r] +
              bih0[g * 512 + h] + bhh0[g * 512 + h];
    }
    float ig = sigm(gg[0]), fg = sigm(gg[1]), gt = tanh_f(gg[2]), og = sigm(gg[3]);
    int si = b * 512 + h;
    float c  = st[C0O + p * 16384 + si];
    float cn = fg * c + ig * gt;
    float hn = og * tanh_f(cn);
    st[H0O + (p ^ 1) * 16384 + si] = hn;
    st[C0O + (p ^ 1) * 16384 + si] = cn;
  }
}

// ---------------- step D: LSTM1 + q_next (proven round 4) ----------------
__global__ __launch_bounds__(256)
void stepD(const float* __restrict__ wih1, const float* __restrict__ whh1,
           const float* __restrict__ bih1, const float* __restrict__ bhh1,
           const float* __restrict__ Wq, float* __restrict__ st, int p) {
  __shared__ float xs[32 * 132];
  __shared__ float wr[12 * 132];
  __shared__ float gp[4 * 32 * 12];
  const int tid = threadIdx.x, wv = tid >> 6, ln = tid & 63;
  const int h0d = blockIdx.x * 2;
  float acc[12];
#pragma unroll
  for (int r = 0; r < 12; ++r) acc[r] = 0.f;
  for (int ch = 0; ch < 8; ++ch) {
    const float* src = (ch < 4) ? (st + H0O + (p ^ 1) * 16384) : (st + H1O + p * 16384);
    const int col0 = (ch & 3) * 128;
#pragma unroll
    for (int i = 0; i < 4; ++i) {
      int e4 = tid * 4 + i * 1024;
      int bs = e4 >> 7, j = e4 & 127;
      *(float4*)(&xs[bs * 132 + j]) = *(const float4*)(src + bs * 512 + col0 + j);
    }
    {
      int e = tid * 4, r = e >> 7, j = e & 127;
      int g = r >> 1, hh = r & 1;
      const float* wsrc = (ch < 4) ? wih1 : whh1;
      long rb = (long)(g * 512 + h0d + hh) * 512 + col0;
      *(float4*)(&wr[r * 132 + j]) = *(const float4*)(&wsrc[rb + j]);
      if (ch < 4 && tid < 128) {
        int rq = e >> 7, j2 = e & 127;
        long rqb = (long)(4 * blockIdx.x + rq) * 512 + col0;
        *(float4*)(&wr[(8 + rq) * 132 + j2]) = *(const float4*)(&Wq[rqb + j2]);
      }
    }
    __syncthreads();
    const int b = tid & 31, j0 = (tid >> 5) * 16;
#pragma unroll
    for (int jj = 0; jj < 16; jj += 4) {
      const float4 xv = *(const float4*)(&xs[b * 132 + j0 + jj]);
#pragma unroll
      for (int r = 0; r < 8; ++r) {
        const float4 w4 = *(const float4*)(&wr[r * 132 + j0 + jj]);
        acc[r] += xv.x * w4.x + xv.y * w4.y + xv.z * w4.z + xv.w * w4.w;
      }
      if (ch < 4) {
#pragma unroll
        for (int r = 8; r < 12; ++r) {
          const float4 w4 = *(const float4*)(&wr[r * 132 + j0 + jj]);
          acc[r] += xv.x * w4.x + xv.y * w4.y + xv.z * w4.z + xv.w * w4.w;
        }
      }
    }
    __syncthreads();
  }
#pragma unroll
  for (int r = 0; r < 12; ++r) acc[r] += __shfl_down(acc[r], 32);
  if (ln < 32) {
#pragma unroll
    for (int r = 0; r < 12; ++r) gp[(wv * 32 + ln) * 12 + r] = acc[r];
  }
  __syncthreads();
  if (tid < 64) {
    const int b = tid & 31, hh = tid >> 5, h = h0d + hh;
    float gg[4];
#pragma unroll
    for (int g = 0; g < 4; ++g) {
      int r = g * 2 + hh;
      gg[g] = gp[(0 * 32 + b) * 12 + r] + gp[(1 * 32 + b) * 12 + r] +
              gp[(2 * 32 + b) * 12 + r] + gp[(3 * 32 + b) * 12 + r] +
              bih1[g * 512 + h] + bhh1[g * 512 + h];
    }
    float ig = sigm(gg[0]), fg = sigm(gg[1]), gt = tanh_f(gg[2]), og = sigm(gg[3]);
    int si = b * 512 + h;
    float c  = st[C1O + p * 16384 + si];
    float cn = fg * c + ig * gt;
    float hn = og * tanh_f(cn);
    st[H1O + (p ^ 1) * 16384 + si] = hn;
    st[C1O + (p ^ 1) * 16384 + si] = cn;
    int r0 = 8 + 2 * hh;
    float q0 = gp[(0 * 32 + b) * 12 + r0]     + gp[(1 * 32 + b) * 12 + r0] +
               gp[(2 * 32 + b) * 12 + r0]     + gp[(3 * 32 + b) * 12 + r0];
    float q1 = gp[(0 * 32 + b) * 12 + r0 + 1] + gp[(1 * 32 + b) * 12 + r0 + 1] +
               gp[(2 * 32 + b) * 12 + r0 + 1] + gp[(3 * 32 + b) * 12 + r0 + 1];
    int o0 = 4 * blockIdx.x + 2 * hh;
    st[QO + b * 1024 + o0]     = q0;
    st[QO + b * 1024 + o0 + 1] = q1;
  }
}

// ---------------- fc tail (step SD-1; h1 parity 0) ----------------
__global__ __launch_bounds__(256)
void fcK(const float* __restrict__ fcw, const float* __restrict__ fcb,
         float* __restrict__ st, float* __restrict__ out) {
  __shared__ float h1s[512];
  const int b = blockIdx.x >> 2, og = (blockIdx.x & 3) * 32;
  const int tid = threadIdx.x, wv = tid >> 6, ln = tid & 63;
  for (int i = tid; i < 512; i += 256) h1s[i] = st[H1O + b * 512 + i];
  __syncthreads();
#pragma unroll
  for (int oi = 0; oi < 8; ++oi) {
    const int o = og + wv * 8 + oi;
    float part = 0.f;
#pragma unroll
    for (int kk = 0; kk < 8; ++kk) {
      int k = kk * 64 + ln;
      part += h1s[k] * fcw[(long)o * 512 + k];
    }
    for (int off = 32; off; off >>= 1) part += __shfl_down(part, off);
    if (ln == 0) {
      float yh = fmaxf(part + fcb[o], 0.f);
      out[((long)b * SD + (SD - 1)) * 128 + o] = yh;
    }
  }
}

extern "C" void kernel_launch(void* const* d_in, const int* in_sizes, int n_in,
                              void* d_out, int out_size, void* d_ws, size_t ws_size,
                              hipStream_t stream) {
  (void)in_sizes; (void)n_in; (void)out_size; (void)ws_size;
  float* out = (float*)d_out;

  const float* E    = (const float*)d_in[0];
  const float* h0   = (const float*)d_in[1];
  const float* c0   = (const float*)d_in[2];
  const float* Wk   = (const float*)d_in[3];
  const float* Wq   = (const float*)d_in[4];
  const float* Wv   = (const float*)d_in[5];
  const float* We   = (const float*)d_in[6];
  const float* wih0 = (const float*)d_in[7];
  const float* whh0 = (const float*)d_in[8];
  const float* bih0 = (const float*)d_in[9];
  const float* bhh0 = (const float*)d_in[10];
  const float* wih1 = (const float*)d_in[11];
  const float* whh1 = (const float*)d_in[12];
  const float* bih1 = (const float*)d_in[13];
  const float* bhh1 = (const float*)d_in[14];
  const float* fcw  = (const float*)d_in[15];
  const float* fcb  = (const float*)d_in[16];

  // ws layout (rounds 5/6 proved ws >= 68.1 MB): key bf16 33.5MB | value bf16 33.5MB | st ~1MB
  u16* key   = (u16*)d_ws;
  u16* value = key + 16777216;
  float* st  = (float*)d_ws + 16777216;   // byte 67,108,864

  gemm_kv<<<dim3(256, 16, 2), 256, 0, stream>>>(E, Wk, Wv, key, value);
  init_state<<<64, 256, 0, stream>>>(h0, c0, st);
  qproj<<<128, 256, 0, stream>>>(h0, Wq, st);

  for (int s = 0; s < SD; ++s) {
    int p = s & 1;
    stepA<<<512, 256, 0, stream>>>(key, We, st);
    stepB<<<288, 256, 0, stream>>>(value, fcw, fcb, st, out, s);
    stepC<<<256, 256, 0, stream>>>(wih0, whh0, bih0, bhh0, st, p);
    stepD<<<256, 256, 0, stream>>>(wih1, whh1, bih1, bhh1, Wq, st, p);
  }
  fcK<<<128, 256, 0, stream>>>(fcw, fcb, st, out);
}